// Round 9
// baseline (362.112 us; speedup 1.0000x reference)
//
#include <hip/hip_runtime.h>
#include <stdint.h>

// Problem constants: B=16, T=1024, N=512
#define BB 16
#define TT 1024
#define NN 512

typedef unsigned short u16;
typedef __bf16 bf16_t;
typedef bf16_t bf16x8 __attribute__((ext_vector_type(8)));
typedef float f32x4 __attribute__((ext_vector_type(4)));

struct alignas(8) U16x4 { u16 x, y, z, w; };
struct alignas(16) F32x4 { float x, y, z, w; };

__device__ __forceinline__ u16 f2bf(float f) {
    union { float f; uint32_t u; } v; v.f = f;
    uint32_t r = v.u + 0x7fffu + ((v.u >> 16) & 1u);
    return (u16)(r >> 16);
}

__device__ __forceinline__ void gload_lds16(const void* g, void* l) {
    __builtin_amdgcn_global_load_lds(
        (const __attribute__((address_space(1))) void*)g,
        (__attribute__((address_space(3))) void*)l, 16, 0, 0);
}

// ---------------------------------------------------------------------------
// Software grid barrier (persistent kernel, 256 blocks all co-resident:
// 48KB LDS -> >=2 blocks/CU capacity on 256 CUs, so no deadlock possible).
// Cross-XCD visibility: __syncthreads drains stores to L2 (hipcc emits
// vmcnt(0) before s_barrier); __threadfence = agent-scope wb/inv of XCD L2
// (gfx940+ memory model); atomicAdd is device-scope by default [m20].
// Monotonic targets, counter zeroed host-side per launch.
// ---------------------------------------------------------------------------
__device__ __forceinline__ void gbar(unsigned* cnt, unsigned target) {
    __syncthreads();
    if (threadIdx.x == 0) {
        __threadfence();                                   // release: wb L2
        atomicAdd(cnt, 1u);
        while (atomicAdd(cnt, 0u) < target)
            __builtin_amdgcn_s_sleep(2);
        __threadfence();                                   // acquire: inv L2
    }
    __syncthreads();
}

// ---------------------------------------------------------------------------
// Device NT GEMM tile: C[128x128 tile at (by,bx)] = A[128,K] * Bt[128,K]^T.
// bf16 in, fp32 accum, BK=32, 4 waves, 4x4 frags of mfma_f32_16x16x32_bf16.
// 3-buffer LDS ring (As at +0, Bs at +24576; 48KB), counted vmcnt(8/4/0).
// Swizzle byte ^= ((row>>1)&3)<<4 both-sides. Verified r5/r7.
// MODE 0: bf16 store; MODE 2: fp32; MODE 3: fp32 + bias[j].
// ---------------------------------------------------------------------------
template<int MODE>
__device__ void dev_gemm(const u16* __restrict__ A, const u16* __restrict__ Bt,
                         void* __restrict__ C, const float* __restrict__ bias,
                         int Nc, int K, int lda, int ldb,
                         int bx, int by, char* smem)
{
    char* AsB = smem;
    char* BsB = smem + 24576;

    const int tid  = threadIdx.x;
    const int wave = tid >> 6;
    const int lane = tid & 63;
    const int arow0 = by * 128;
    const int brow0 = bx * 128;
    const int wr = (wave >> 1) * 64;
    const int wc = (wave & 1) * 64;

    const int srow = tid >> 2;
    const int sf   = ((srow >> 1) & 3) << 4;
    const int gcol = ((tid & 3) << 4) ^ sf;
    const char* Asrc = (const char*)A  + (long)(arow0 + srow) * lda * 2 + gcol;
    const char* Bsrc = (const char*)Bt + (long)(brow0 + srow) * ldb * 2 + gcol;
    const long rstepA = (long)64 * lda * 2;
    const long rstepB = (long)64 * ldb * 2;

    f32x4 zero = {0.f, 0.f, 0.f, 0.f};
    f32x4 acc[4][4];
#pragma unroll
    for (int i = 0; i < 4; i++)
#pragma unroll
        for (int j = 0; j < 4; j++) acc[i][j] = zero;

    const int kTiles = K >> 5;

    auto stage = [&](int buf, int kt) {
        const long kb = (long)kt * 64;
        char* ad = AsB + buf * 8192 + tid * 16;
        char* bd = BsB + buf * 8192 + tid * 16;
        gload_lds16(Asrc + kb,          ad);
        gload_lds16(Bsrc + kb,          bd);
        gload_lds16(Asrc + rstepA + kb, ad + 4096);
        gload_lds16(Bsrc + rstepB + kb, bd + 4096);
    };

    stage(0, 0);
    stage(1, 1);
    int cur = 0, nxt2 = 2;
    const int kbyte = (lane >> 4) << 4;
    const int rA = lane & 15;

    for (int kt = 0; kt < kTiles; ++kt) {
        if (kt + 2 < kTiles) {
            stage(nxt2, kt + 2);
            asm volatile("s_waitcnt vmcnt(8)" ::: "memory");
        } else if (kt + 1 < kTiles) {
            asm volatile("s_waitcnt vmcnt(4)" ::: "memory");
        } else {
            asm volatile("s_waitcnt vmcnt(0)" ::: "memory");
        }
        __builtin_amdgcn_s_barrier();
        asm volatile("" ::: "memory");

        bf16x8 av[4], bv[4];
        const char* as = AsB + cur * 8192;
        const char* bs = BsB + cur * 8192;
#pragma unroll
        for (int m = 0; m < 4; m++) {
            const int row = wr + m * 16 + rA;
            av[m] = *(const bf16x8*)(as + row * 64 + (kbyte ^ (((row >> 1) & 3) << 4)));
        }
#pragma unroll
        for (int n = 0; n < 4; n++) {
            const int row = wc + n * 16 + rA;
            bv[n] = *(const bf16x8*)(bs + row * 64 + (kbyte ^ (((row >> 1) & 3) << 4)));
        }
#pragma unroll
        for (int m = 0; m < 4; m++)
#pragma unroll
            for (int n = 0; n < 4; n++)
                acc[m][n] = __builtin_amdgcn_mfma_f32_16x16x32_bf16(av[m], bv[n], acc[m][n], 0, 0, 0);

        asm volatile("" ::: "memory");
        __builtin_amdgcn_s_barrier();
        cur  = (cur  == 2) ? 0 : cur  + 1;
        nxt2 = (nxt2 == 2) ? 0 : nxt2 + 1;
    }

    // epilogue. C/D layout: col = lane&15, row = (lane>>4)*4 + r  [m89/m91]
    const int r0 = (lane >> 4) << 2;
    const int cl = lane & 15;
#pragma unroll
    for (int m = 0; m < 4; m++) {
        const long gm = (long)arow0 + wr + m * 16 + r0;
#pragma unroll
        for (int n = 0; n < 4; n++) {
            const long gn = (long)brow0 + wc + n * 16 + cl;
            if (MODE == 0) {
                u16* O = (u16*)C;
#pragma unroll
                for (int r = 0; r < 4; r++)
                    O[(gm + r) * Nc + gn] = f2bf(acc[m][n][r]);
            } else {
                float* O = (float*)C;
                const float bb = (MODE == 3) ? bias[gn] : 0.f;
#pragma unroll
                for (int r = 0; r < 4; r++)
                    O[(gm + r) * Nc + gn] = acc[m][n][r] + bb;
            }
        }
    }
}

// ---------------------------------------------------------------------------
// Persistent megakernel: all 8 phases, grid 256 x 256thr, software barriers.
//   P0 cvt: x -> xb[B,T,N] + xT[B,N,T]; weights -> [Wq|Wk|WvT|Wp]
//   P1 G[b]  = xT[b] xT[b]^T       (K=1024, bf16)
//   P2 H[b]  = Wq G[b]             (K=512,  bf16; G symmetric)
//   P3 S[b]  = H[b] Wk^T           (K=512,  fp32)
//   P4 attn  = softmax(S*512^-.5)  bf16 in-place (row ld 1024 u16)
//   P5 Rt[b] = (attn[b] Wv)^T = NT(WvT, attn)    (bf16)
//   P6 Z[b]  = Wp attn[b] Wv  = NT(Wp, Rt)       (bf16)
//   P7 out   = NT(xb, Z) + bp      (fp32)
// ---------------------------------------------------------------------------
__global__ __launch_bounds__(256)
void mega(const float* __restrict__ x,
          const float* __restrict__ Wq, const float* __restrict__ Wk,
          const float* __restrict__ Wv, const float* __restrict__ Wp,
          const float* __restrict__ bp, float* __restrict__ out,
          u16* xb, u16* xT, u16* wb, u16* G, u16* H, float* S, u16* Rt, u16* Z,
          unsigned* cnt)
{
    __shared__ __align__(16) char smem[49152];

    const int bid = blockIdx.x;
    const int i   = threadIdx.x;
    const long NSQ = (long)NN * NN;
    unsigned tgt = 0;

    // ---------------- P0: conversions + transposes ----------------
    {
        u16 (*tile)[70] = (u16 (*)[70])smem;   // 64x70 u16 = 8960 B
        for (int u = bid; u < 2304; u += 256) {
            if (u < 2048) {
                const int b  = u >> 7;
                const int t0 = ((u & 127) >> 3) * 64;
                const int n0 = (u & 7) * 64;
#pragma unroll
                for (int rep = 0; rep < 4; rep++) {
                    const int lin = rep * 256 + i;
                    const int r = lin >> 4, c4 = (lin & 15) * 4;
                    const long src = ((long)(b * TT + t0 + r)) * NN + n0 + c4;
                    F32x4 f = *(const F32x4*)&x[src];
                    U16x4 u4;
                    u4.x = f2bf(f.x); u4.y = f2bf(f.y); u4.z = f2bf(f.z); u4.w = f2bf(f.w);
                    *(U16x4*)&xb[src] = u4;
                    tile[r][c4] = u4.x; tile[r][c4 + 1] = u4.y;
                    tile[r][c4 + 2] = u4.z; tile[r][c4 + 3] = u4.w;
                }
                __syncthreads();
#pragma unroll
                for (int rep = 0; rep < 4; rep++) {
                    const int lin = rep * 256 + i;
                    const int n = lin >> 4, t4 = (lin & 15) * 4;
                    U16x4 u4;
                    u4.x = tile[t4][n]; u4.y = tile[t4 + 1][n];
                    u4.z = tile[t4 + 2][n]; u4.w = tile[t4 + 3][n];
                    *(U16x4*)&xT[((long)(b * NN + n0 + n)) * TT + t0 + t4] = u4;
                }
                __syncthreads();
            } else {
                const int idx = u - 2048;
                const int w = idx >> 6, wt = idx & 63;
                const int r0 = (wt >> 3) * 64, c0 = (wt & 7) * 64;
                const float* src = (w == 0) ? Wq : (w == 1) ? Wk : (w == 2) ? Wv : Wp;
                u16* dst = wb + w * 262144;
                if (w != 2) {
#pragma unroll
                    for (int rep = 0; rep < 4; rep++) {
                        const int lin = rep * 256 + i;
                        const int r = lin >> 4, c4 = (lin & 15) * 4;
                        F32x4 f = *(const F32x4*)&src[(r0 + r) * 512 + c0 + c4];
                        U16x4 u4;
                        u4.x = f2bf(f.x); u4.y = f2bf(f.y); u4.z = f2bf(f.z); u4.w = f2bf(f.w);
                        *(U16x4*)&dst[(r0 + r) * 512 + c0 + c4] = u4;
                    }
                    __syncthreads(); __syncthreads();
                } else {   // WvT[i,m] = Wv[m,i]
#pragma unroll
                    for (int rep = 0; rep < 4; rep++) {
                        const int lin = rep * 256 + i;
                        const int r = lin >> 4, c4 = (lin & 15) * 4;
                        F32x4 f = *(const F32x4*)&src[(r0 + r) * 512 + c0 + c4];
                        tile[r][c4]     = f2bf(f.x); tile[r][c4 + 1] = f2bf(f.y);
                        tile[r][c4 + 2] = f2bf(f.z); tile[r][c4 + 3] = f2bf(f.w);
                    }
                    __syncthreads();
#pragma unroll
                    for (int rep = 0; rep < 4; rep++) {
                        const int lin = rep * 256 + i;
                        const int n = lin >> 4, t4 = (lin & 15) * 4;
                        U16x4 u4;
                        u4.x = tile[t4][n]; u4.y = tile[t4 + 1][n];
                        u4.z = tile[t4 + 2][n]; u4.w = tile[t4 + 3][n];
                        *(U16x4*)&dst[(c0 + n) * 512 + r0 + t4] = u4;
                    }
                    __syncthreads();
                }
            }
        }
    }
    gbar(cnt, tgt += 256);

    // ---------------- P1: G[b] = xT[b] xT[b]^T ----------------
    {
        const int b = bid >> 4, t = bid & 15;
        dev_gemm<0>(xT + (long)b * NN * TT, xT + (long)b * NN * TT,
                    G + (long)b * NSQ, nullptr, NN, TT, TT, TT, t & 3, t >> 2, smem);
    }
    gbar(cnt, tgt += 256);

    // ---------------- P2: H[b] = Wq G[b] ----------------
    {
        const int b = bid >> 4, t = bid & 15;
        dev_gemm<0>(wb, G + (long)b * NSQ,
                    H + (long)b * NSQ, nullptr, NN, NN, NN, NN, t & 3, t >> 2, smem);
    }
    gbar(cnt, tgt += 256);

    // ---------------- P3: S[b] = H[b] Wk^T (fp32) ----------------
    {
        const int b = bid >> 4, t = bid & 15;
        dev_gemm<2>(H + (long)b * NSQ, wb + 262144,
                    S + (long)b * NSQ, nullptr, NN, NN, NN, NN, t & 3, t >> 2, smem);
    }
    gbar(cnt, tgt += 256);

    // ---------------- P4: softmax rows, bf16 in-place ----------------
    {
        float* red = (float*)smem;
        const int lane = i & 63, wave = i >> 6;
        const float scale = 0.04419417382415922f;  // 512^-0.5
        for (int it = 0; it < 32; ++it) {
            const long r = (long)bid * 32 + it;
            float* row = S + r * 512;
            float a = row[i] * scale;
            float b = row[i + 256] * scale;

            float m = fmaxf(a, b);
#pragma unroll
            for (int o = 32; o; o >>= 1) m = fmaxf(m, __shfl_xor(m, o, 64));
            if (lane == 0) red[wave] = m;
            __syncthreads();
            m = fmaxf(fmaxf(red[0], red[1]), fmaxf(red[2], red[3]));

            float e0 = __expf(a - m), e1 = __expf(b - m);
            float s = e0 + e1;
#pragma unroll
            for (int o = 32; o; o >>= 1) s += __shfl_xor(s, o, 64);
            if (lane == 0) red[wave + 4] = s;
            __syncthreads();
            s = red[4] + red[5] + red[6] + red[7];
            const float inv = 1.f / s;

            u16* P = (u16*)row;
            P[i]       = f2bf(e0 * inv);
            P[i + 256] = f2bf(e1 * inv);
            __syncthreads();
        }
    }
    gbar(cnt, tgt += 256);

    // ---------------- P5: Rt[b] = NT(WvT, attn[b]) ----------------
    {
        const int b = bid >> 4, t = bid & 15;
        dev_gemm<0>(wb + 2 * 262144, (const u16*)(S + (long)b * NSQ),
                    Rt + (long)b * NSQ, nullptr, NN, NN, NN, 1024, t & 3, t >> 2, smem);
    }
    gbar(cnt, tgt += 256);

    // ---------------- P6: Z[b] = NT(Wp, Rt[b]) ----------------
    {
        const int b = bid >> 4, t = bid & 15;
        dev_gemm<0>(wb + 3 * 262144, Rt + (long)b * NSQ,
                    Z + (long)b * NSQ, nullptr, NN, NN, NN, NN, t & 3, t >> 2, smem);
    }
    gbar(cnt, tgt += 256);

    // ---------------- P7: out = NT(xb, Z) + bp (fp32) ----------------
    for (int u = bid; u < 512; u += 256) {
        const int b = u >> 5, rem = u & 31;
        dev_gemm<3>(xb + (long)b * TT * NN, Z + (long)b * NSQ,
                    out + (long)b * TT * NN, bp, NN, NN, NN, NN,
                    rem & 3, rem >> 2, smem);
    }
}

// ---------------------------------------------------------------------------
extern "C" void kernel_launch(void* const* d_in, const int* in_sizes, int n_in,
                              void* d_out, int out_size, void* d_ws, size_t ws_size,
                              hipStream_t stream)
{
    (void)in_sizes; (void)n_in; (void)out_size; (void)ws_size;
    const float* x  = (const float*)d_in[0];
    const float* Wq = (const float*)d_in[1];
    const float* Wk = (const float*)d_in[2];
    const float* Wv = (const float*)d_in[3];
    const float* Wp = (const float*)d_in[4];
    const float* bp = (const float*)d_in[5];
    float* out = (float*)d_out;

    char* ws = (char*)d_ws;
    size_t o = 0;
    auto alloc = [&](size_t bytes) {
        char* p = ws + o;
        o = (o + bytes + 255) & ~(size_t)255;
        return p;
    };
    unsigned* cnt = (unsigned*)alloc(256);              // software barrier counter
    u16* xb = (u16*)alloc((size_t)BB * TT * NN * 2);    // x bf16 [B,T,N]
    u16* xT = (u16*)alloc((size_t)BB * NN * TT * 2);    // x^T bf16 [B,N,T]
    u16* wb = (u16*)alloc((size_t)4 * NN * NN * 2);     // [Wq|Wk|WvT|Wp]
    u16* G  = (u16*)alloc((size_t)BB * NN * NN * 2);
    u16* H  = (u16*)alloc((size_t)BB * NN * NN * 2);
    float* S = (float*)alloc((size_t)BB * NN * NN * 4); // logits / attn in-place
    u16* Rt = (u16*)alloc((size_t)BB * NN * NN * 2);
    u16* Z  = (u16*)alloc((size_t)BB * NN * NN * 2);

    hipMemsetAsync(cnt, 0, 256, stream);
    mega<<<dim3(256), dim3(256), 0, stream>>>(
        x, Wq, Wk, Wv, Wp, bp, out,
        xb, xT, wb, G, H, S, Rt, Z, cnt);
}